// Round 1
// baseline (140.485 us; speedup 1.0000x reference)
//
#include <hip/hip_runtime.h>

#define SPB 4  // samples per block

__global__ __launch_bounds__(256) void model_fused(
    const float* __restrict__ x, const float* __restrict__ y, const float* __restrict__ t,
    const float* __restrict__ embW1, const float* __restrict__ embb1,
    const float* __restrict__ embwa, const float* __restrict__ embwb,
    const float* __restrict__ embW2, const float* __restrict__ embb2,
    const float* __restrict__ mixW1, const float* __restrict__ mixb1,
    const float* __restrict__ mixwa, const float* __restrict__ mixwb,
    const float* __restrict__ mixW2, const float* __restrict__ mixb2,
    const float* __restrict__ outW0, const float* __restrict__ outb0,
    const float* __restrict__ outwa0, const float* __restrict__ outwb0,
    const float* __restrict__ outWh, const float* __restrict__ outbh,
    const float* __restrict__ outwah, const float* __restrict__ outwbh,
    const float* __restrict__ outWf1, const float* __restrict__ outbf1,
    const float* __restrict__ outwaf, const float* __restrict__ outwbf,
    const float* __restrict__ outWf2, const float* __restrict__ outbf2,
    float* __restrict__ out, int N)
{
    __shared__ float sC[3][64];        // per-channel region factors (region 0 == 1.0 implicit)
    __shared__ float sw[SPB][64];      // wave(u) per sample
    __shared__ float se[SPB][256];     // mixer output e
    __shared__ float sh[2][SPB][64];   // head double-buffer
    __shared__ float sMixW1[32], sMixb1[8], sMixW2[8];

    const int tid = threadIdx.x;
    const int n0  = blockIdx.x * SPB;

    // ---- stage tiny mixer params into LDS ----
    if (tid < 32)       sMixW1[tid]      = mixW1[tid];
    else if (tid < 40)  sMixb1[tid - 32] = mixb1[tid - 32];
    else if (tid < 48)  sMixW2[tid - 40] = mixW2[tid - 40];

    // ---- phase 1: region factors C_r[ch] and w = wave(u) per sample ----
    {
        const int ch = tid & 63;
        const int sm = tid >> 6;
        const float w0 = embW1[ch], w1 = embW1[64 + ch], w2 = embW1[128 + ch];
        if (sm == 0) {
            // PERTS: (r=0.01,s=3), (0.05,5), (0.09,7); grid symmetric -> <sin d> = 0,
            // <cos d> factorizes per axis: g_s(w) = (1 + 2*sum cos(d_k w))/s
            float ga = (1.f + 2.f*__cosf(0.01f*w0))
                     * (1.f + 2.f*__cosf(0.01f*w1))
                     * (1.f + 2.f*__cosf(0.01f*w2)) * (1.f/27.f);
            float gb = (1.f + 2.f*(__cosf(0.025f*w0) + __cosf(0.05f*w0)))
                     * (1.f + 2.f*(__cosf(0.025f*w1) + __cosf(0.05f*w1)))
                     * (1.f + 2.f*(__cosf(0.025f*w2) + __cosf(0.05f*w2))) * (1.f/125.f);
            float gc = (1.f + 2.f*(__cosf(0.03f*w0) + __cosf(0.06f*w0) + __cosf(0.09f*w0)))
                     * (1.f + 2.f*(__cosf(0.03f*w1) + __cosf(0.06f*w1) + __cosf(0.09f*w1)))
                     * (1.f + 2.f*(__cosf(0.03f*w2) + __cosf(0.06f*w2) + __cosf(0.09f*w2))) * (1.f/343.f);
            sC[0][ch] = ga; sC[1][ch] = gb; sC[2][ch] = gc;
        }
        const int n  = n0 + sm;
        const int ns = (n < N) ? n : (N - 1);
        float u = x[ns]*w0 + y[ns]*w1 + t[ns]*w2 + embb1[ch];
        sw[sm][ch] = embwa[0]*__sinf(u) + embwb[0]*__cosf(u);
    }
    __syncthreads();

    // ---- phase 2: 4-region projection (thread owns channel c) + inline mixer ----
    {
        const int c = tid;
        float a0[SPB], a1[SPB], a2[SPB], a3[SPB];
        #pragma unroll
        for (int n = 0; n < SPB; ++n) { a0[n]=0.f; a1[n]=0.f; a2[n]=0.f; a3[n]=0.f; }

        #pragma unroll 4
        for (int ch = 0; ch < 64; ++ch) {
            const float wr = embW2[ch*256 + c];          // coalesced across threads
            const float c1 = sC[0][ch], c2 = sC[1][ch], c3 = sC[2][ch];
            #pragma unroll
            for (int n = 0; n < SPB; ++n) {
                const float tn = sw[n][ch] * wr;
                a0[n] += tn;
                a1[n] = fmaf(tn, c1, a1[n]);
                a2[n] = fmaf(tn, c2, a2[n]);
                a3[n] = fmaf(tn, c3, a3[n]);
            }
        }

        const float mwa = mixwa[0], mwb = mixwb[0], mb2 = mixb2[0];
        const float bb2 = embb2[c];
        #pragma unroll
        for (int n = 0; n < SPB; ++n) {
            const float s0 = a0[n]+bb2, s1 = a1[n]+bb2, s2 = a2[n]+bb2, s3 = a3[n]+bb2;
            float ev = mb2;
            #pragma unroll
            for (int j = 0; j < 8; ++j) {
                float p = fmaf(s0, sMixW1[j],
                          fmaf(s1, sMixW1[8 + j],
                          fmaf(s2, sMixW1[16 + j],
                          fmaf(s3, sMixW1[24 + j], sMixb1[j]))));
                ev = fmaf(mwa*__sinf(p) + mwb*__cosf(p), sMixW2[j], ev);
            }
            se[n][c] = ev;
        }
    }
    __syncthreads();

    // ---- phase 3: output head (thread = (sample n, feature f)) ----
    const int n = tid >> 6, f = tid & 63;
    {
        float a = outb0[f];
        for (int k = 0; k < 256; ++k)
            a = fmaf(se[n][k], outW0[k*64 + f], a);   // se broadcast (wave-uniform n)
        sh[0][n][f] = outwa0[0]*__sinf(a) + outwb0[0]*__cosf(a);
    }
    __syncthreads();

    int cur = 0;
    #pragma unroll
    for (int i = 0; i < 3; ++i) {
        float a = outbh[i*64 + f];
        const float* W = outWh + i*4096;
        #pragma unroll 8
        for (int k = 0; k < 64; ++k)
            a = fmaf(sh[cur][n][k], W[k*64 + f], a);
        sh[1 - cur][n][f] = outwah[i]*__sinf(a) + outwbh[i]*__cosf(a);
        __syncthreads();
        cur ^= 1;
    }
    {
        float a = outbf1[f];
        #pragma unroll 8
        for (int k = 0; k < 64; ++k)
            a = fmaf(sh[cur][n][k], outWf1[k*64 + f], a);
        sh[1 - cur][n][f] = outwaf[0]*__sinf(a) + outwbf[0]*__cosf(a);
        __syncthreads();
        cur ^= 1;
    }
    if (tid < SPB*3) {
        const int nn = tid / 3, o = tid - nn*3;
        float a = outbf2[o];
        #pragma unroll 8
        for (int k = 0; k < 64; ++k)
            a = fmaf(sh[cur][nn][k], outWf2[k*3 + o], a);
        const int gn = n0 + nn;
        if (gn < N) out[gn*3 + o] = a;
    }
}

extern "C" void kernel_launch(void* const* d_in, const int* in_sizes, int n_in,
                              void* d_out, int out_size, void* d_ws, size_t ws_size,
                              hipStream_t stream) {
    const float* x      = (const float*)d_in[0];
    const float* y      = (const float*)d_in[1];
    const float* t      = (const float*)d_in[2];
    const float* embW1  = (const float*)d_in[3];
    const float* embb1  = (const float*)d_in[4];
    const float* embwa  = (const float*)d_in[5];
    const float* embwb  = (const float*)d_in[6];
    const float* embW2  = (const float*)d_in[7];
    const float* embb2  = (const float*)d_in[8];
    const float* mixW1  = (const float*)d_in[9];
    const float* mixb1  = (const float*)d_in[10];
    const float* mixwa  = (const float*)d_in[11];
    const float* mixwb  = (const float*)d_in[12];
    const float* mixW2  = (const float*)d_in[13];
    const float* mixb2  = (const float*)d_in[14];
    const float* outW0  = (const float*)d_in[15];
    const float* outb0  = (const float*)d_in[16];
    const float* outwa0 = (const float*)d_in[17];
    const float* outwb0 = (const float*)d_in[18];
    const float* outWh  = (const float*)d_in[19];
    const float* outbh  = (const float*)d_in[20];
    const float* outwah = (const float*)d_in[21];
    const float* outwbh = (const float*)d_in[22];
    const float* outWf1 = (const float*)d_in[23];
    const float* outbf1 = (const float*)d_in[24];
    const float* outwaf = (const float*)d_in[25];
    const float* outwbf = (const float*)d_in[26];
    const float* outWf2 = (const float*)d_in[27];
    const float* outbf2 = (const float*)d_in[28];
    float* out = (float*)d_out;

    const int N = in_sizes[0];
    const int blocks = (N + SPB - 1) / SPB;
    model_fused<<<blocks, 256, 0, stream>>>(
        x, y, t,
        embW1, embb1, embwa, embwb, embW2, embb2,
        mixW1, mixb1, mixwa, mixwb, mixW2, mixb2,
        outW0, outb0, outwa0, outwb0,
        outWh, outbh, outwah, outwbh,
        outWf1, outbf1, outwaf, outwbf, outWf2, outbf2,
        out, N);
}